// Round 10
// baseline (529.618 us; speedup 1.0000x reference)
//
#include <hip/hip_runtime.h>
#include <math.h>

#define NU_    100000
#define NI_    50000
#define NB_    20000
#define DIM    64
#define E_UI_  2000000
#define E_BI_  600000
#define NPROP  (2 * E_UI_)
#define NTOT   (NU_ + NI_)
#define BATCH  4096
#define NBIN_P ((NTOT + 255) / 256)   // 586
#define NBIN_B ((NB_  + 255) / 256)   // 79

#define CAST_BLOCKS ((NTOT * 16 + 255) / 256)   // 9375
#define HISTP_BLOCKS 512
#define HISTB_BLOCKS 64
#define MSP_BLOCKS   768
#define MSB_BLOCKS   96
#define SCORE_BLOCKS (BATCH / 4)                // 1024, one wave per sample

// ---------------------------------------------------------------------------
// bf16 helpers
__device__ __forceinline__ float bflo(unsigned int u) {
    return __uint_as_float(u << 16);
}
__device__ __forceinline__ float bfhi(unsigned int u) {
    return __uint_as_float(u & 0xFFFF0000u);
}
__device__ __forceinline__ unsigned short f2bf(float f) {         // RNE
    unsigned int u = __float_as_uint(f);
    u += 0x7FFFu + ((u >> 16) & 1u);
    return (unsigned short)(u >> 16);
}
__device__ __forceinline__ unsigned int pack2(float a, float b) {
    return (unsigned int)f2bf(a) | ((unsigned int)f2bf(b) << 16);
}

// ---------------------------------------------------------------------------
// Fused: bf16 cast (blocks [0,CAST)) + bin histogram P (next 512) + B (next 64)
__global__ void prep_kernel(const float4* __restrict__ uf4,
                            const float4* __restrict__ itf4,
                            uint2* __restrict__ feats_out,
                            const int* __restrict__ prows,
                            const int* __restrict__ brows,
                            int* __restrict__ bcntP,
                            int* __restrict__ bcntB) {
    __shared__ int lcnt[NBIN_P];
    int bid = blockIdx.x;
    if (bid < CAST_BLOCKS) {
        int i = bid * 256 + threadIdx.x;
        const int nuq = NU_ * 16;
        float4 v = (i < nuq) ? uf4[i] : itf4[i - nuq];
        uint2 o;
        o.x = pack2(v.x, v.y);
        o.y = pack2(v.z, v.w);
        feats_out[i] = o;
        return;
    }
    const int* rows; int n, nbin, vb, vgrid; int* bcnt;
    if (bid < CAST_BLOCKS + HISTP_BLOCKS) {
        rows = prows; n = NPROP; nbin = NBIN_P;
        vb = bid - CAST_BLOCKS; vgrid = HISTP_BLOCKS; bcnt = bcntP;
    } else {
        rows = brows; n = E_BI_; nbin = NBIN_B;
        vb = bid - CAST_BLOCKS - HISTP_BLOCKS; vgrid = HISTB_BLOCKS; bcnt = bcntB;
    }
    for (int i = threadIdx.x; i < nbin; i += 256) lcnt[i] = 0;
    __syncthreads();
    int stride = vgrid * 256 * 4;
    for (int base = vb * 256 * 4; base < n; base += stride) {
        #pragma unroll
        for (int j = 0; j < 4; ++j) {
            int i = base + j * 256 + threadIdx.x;
            if (i < n) atomicAdd(&lcnt[rows[i] >> 8], 1);
        }
    }
    __syncthreads();
    for (int i = threadIdx.x; i < nbin; i += 256)
        if (lcnt[i] > 0) atomicAdd(&bcnt[i], lcnt[i]);
}

// ---------------------------------------------------------------------------
// Exclusive scan of bcnt -> binoff, gcur. Block 0: P, block 1: B.
__global__ void scan_kernel(const int* __restrict__ bcntP, int* __restrict__ binoffP,
                            int* __restrict__ gcurP,
                            const int* __restrict__ bcntB, int* __restrict__ binoffB,
                            int* __restrict__ gcurB) {
    __shared__ int tmp[1024];
    const int* bcnt; int* binoff; int* gcur; int nbin;
    if (blockIdx.x == 0) { bcnt = bcntP; binoff = binoffP; gcur = gcurP; nbin = NBIN_P; }
    else                 { bcnt = bcntB; binoff = binoffB; gcur = gcurB; nbin = NBIN_B; }
    int t = threadIdx.x;
    int x = (t < nbin) ? bcnt[t] : 0;
    tmp[t] = x;
    __syncthreads();
    for (int o = 1; o < 1024; o <<= 1) {
        int y = (t >= o) ? tmp[t - o] : 0;
        __syncthreads();
        tmp[t] += y;
        __syncthreads();
    }
    if (t < nbin) {
        int v = tmp[t] - x;
        binoff[t] = v;
        gcur[t]   = v;
    }
}

// ---------------------------------------------------------------------------
// Fused LDS-staged multisplit (P: blocks [0,768), B: [768,864)).
// 4 edges/thread per barrier cycle (R7-proven); per-thread drain.
// payload = ((row & 255) << 24) | col
__global__ void multisplit_kernel(const int* __restrict__ prows,
                                  const int* __restrict__ pcols,
                                  const int* __restrict__ brows,
                                  const int* __restrict__ bcols,
                                  int* __restrict__ gcurP,
                                  unsigned int* __restrict__ binnedP,
                                  int* __restrict__ gcurB,
                                  unsigned int* __restrict__ binnedB) {
    constexpr int BUF = 16;
    __shared__ int cnt[NBIN_P];
    __shared__ int basep[NBIN_P];
    __shared__ unsigned int stage[NBIN_P][BUF];
    const int *rows, *cols; int n, nbin, vb, vgrid;
    int* gcur; unsigned int* binned;
    if (blockIdx.x < MSP_BLOCKS) {
        rows = prows; cols = pcols; n = NPROP; nbin = NBIN_P;
        vb = blockIdx.x; vgrid = MSP_BLOCKS; gcur = gcurP; binned = binnedP;
    } else {
        rows = brows; cols = bcols; n = E_BI_; nbin = NBIN_B;
        vb = blockIdx.x - MSP_BLOCKS; vgrid = MSB_BLOCKS; gcur = gcurB; binned = binnedB;
    }
    for (int i = threadIdx.x; i < nbin; i += 256) cnt[i] = 0;
    __syncthreads();
    int stride = vgrid * 256 * 4;
    for (int base = vb * 256 * 4; base < n; base += stride) {
        int bin[4], pos[4];
        unsigned int payload[4];
        #pragma unroll
        for (int j = 0; j < 4; ++j) {
            int i = base + j * 256 + threadIdx.x;   // coalesced per step
            pos[j] = -1;
            if (i < n) {
                int r = rows[i];
                int c = cols[i];
                bin[j] = r >> 8;
                payload[j] = ((unsigned int)(r & 255) << 24) | (unsigned int)c;
                pos[j] = atomicAdd(&cnt[bin[j]], 1);
                if (pos[j] < BUF) stage[bin[j]][pos[j]] = payload[j];
            }
        }
        __syncthreads();
        #pragma unroll
        for (int j = 0; j < 4; ++j)
            if (pos[j] == BUF)                 // unique leader per bin
                basep[bin[j]] = atomicAdd(&gcur[bin[j]], cnt[bin[j]]);
        __syncthreads();
        #pragma unroll
        for (int j = 0; j < 4; ++j) {
            if (pos[j] >= BUF) {
                binned[basep[bin[j]] + pos[j]] = payload[j];
                if (pos[j] == BUF) {
                    int b0 = basep[bin[j]];
                    #pragma unroll
                    for (int q = 0; q < BUF; ++q) binned[b0 + q] = stage[bin[j]][q];
                    cnt[bin[j]] = 0;
                }
            }
        }
        __syncthreads();
    }
    // per-thread drain: 256 independent atomic+store chains
    for (int b = threadIdx.x; b < nbin; b += 256) {
        int c = cnt[b];
        if (c > 0) {
            int b0 = atomicAdd(&gcur[b], c);
            for (int j = 0; j < c; ++j) binned[b0 + j] = stage[b][j];
        }
    }
}

// ---------------------------------------------------------------------------
// Fused per-bin CSR build (P: blocks [0,586), B: [586,665)).
__global__ void bin_csr_kernel(const unsigned int* __restrict__ binnedP,
                               const int* __restrict__ binoffP,
                               int* __restrict__ offP, int* __restrict__ degP,
                               float* __restrict__ invsP, int* __restrict__ cvP,
                               const unsigned int* __restrict__ binnedB,
                               const int* __restrict__ binoffB,
                               int* __restrict__ offB, int* __restrict__ degB,
                               int* __restrict__ cvB) {
    __shared__ int cnt[256];
    __shared__ int cur[256];
    __shared__ int scanbuf[256];
    const unsigned int* binned; const int* binoff;
    int* off; int* deg; float* invs; int* cv;
    int b, nbin, n, nrows;
    if (blockIdx.x < NBIN_P) {
        b = blockIdx.x; binned = binnedP; binoff = binoffP; n = NPROP;
        nbin = NBIN_P; nrows = NTOT;
        off = offP; deg = degP; invs = invsP; cv = cvP;
    } else {
        b = blockIdx.x - NBIN_P; binned = binnedB; binoff = binoffB; n = E_BI_;
        nbin = NBIN_B; nrows = NB_;
        off = offB; deg = degB; invs = (float*)0; cv = cvB;
    }
    int t = threadIdx.x;
    int rowbase = b << 8;
    cnt[t] = 0;
    __syncthreads();
    int s = binoff[b];
    int e = (b + 1 < nbin) ? binoff[b + 1] : n;
    for (int i = s + t; i < e; i += 256)
        atomicAdd(&cnt[binned[i] >> 24], 1);
    __syncthreads();
    int x = cnt[t];
    scanbuf[t] = x;
    __syncthreads();
    for (int o = 1; o < 256; o <<= 1) {
        int y = (t >= o) ? scanbuf[t - o] : 0;
        __syncthreads();
        scanbuf[t] += y;
        __syncthreads();
    }
    int base = s + scanbuf[t] - x;
    cur[t] = base;
    if (rowbase + t < nrows) {
        off[rowbase + t] = base;
        deg[rowbase + t] = x;
        if (invs) invs[rowbase + t] = 1.0f / (sqrtf((float)x) + 1e-8f);
    }
    __syncthreads();
    for (int i = s + t; i < e; i += 256) {
        unsigned int p = binned[i];
        int slot = atomicAdd(&cur[p >> 24], 1);
        cv[slot] = (int)(p & 0xFFFFFFu);
    }
}

// ---------------------------------------------------------------------------
// 8 lanes/row, uint4 = 8 bf16 per lane. 8 rows/wave, 32 rows per 256-block.
__device__ __forceinline__ void fma8(float* s, float v, uint4 x) {
    s[0] = fmaf(v, bflo(x.x), s[0]);
    s[1] = fmaf(v, bfhi(x.x), s[1]);
    s[2] = fmaf(v, bflo(x.y), s[2]);
    s[3] = fmaf(v, bfhi(x.y), s[3]);
    s[4] = fmaf(v, bflo(x.z), s[4]);
    s[5] = fmaf(v, bfhi(x.z), s[5]);
    s[6] = fmaf(v, bflo(x.w), s[6]);
    s[7] = fmaf(v, bfhi(x.w), s[7]);
}
__device__ __forceinline__ uint4 pack8(const float* s) {
    uint4 o;
    o.x = pack2(s[0], s[1]);
    o.y = pack2(s[2], s[3]);
    o.z = pack2(s[4], s[5]);
    o.w = pack2(s[6], s[7]);
    return o;
}

// Layer 1: sum = Σ invs[c]·feats[c]; acc16[r] = feats[r] + invs[r]·sum;
//          f1s16[r] = invs[r]²·sum
__global__ void layer1_kernel(const int* __restrict__ off,
                              const int* __restrict__ deg,
                              const int* __restrict__ cv,
                              const float* __restrict__ invs,
                              const uint4* __restrict__ feats16,
                              uint4* __restrict__ f1s16,
                              uint4* __restrict__ acc16) {
    int wave = blockIdx.x * (blockDim.x >> 6) + (threadIdx.x >> 6);
    int sub  = (threadIdx.x >> 3) & 7;
    int l    = threadIdx.x & 7;
    int row  = wave * 8 + sub;
    if (row >= NTOT) return;
    int s = off[row], d = deg[row];
    float sum[8] = {0.f, 0.f, 0.f, 0.f, 0.f, 0.f, 0.f, 0.f};
    int k = 0;
    for (; k + 4 <= d; k += 4) {
        int c0 = cv[s + k + 0];
        int c1 = cv[s + k + 1];
        int c2 = cv[s + k + 2];
        int c3 = cv[s + k + 3];
        float w0 = invs[c0], w1 = invs[c1], w2 = invs[c2], w3 = invs[c3];
        uint4 x0 = feats16[(size_t)c0 * 8 + l];
        uint4 x1 = feats16[(size_t)c1 * 8 + l];
        uint4 x2 = feats16[(size_t)c2 * 8 + l];
        uint4 x3 = feats16[(size_t)c3 * 8 + l];
        fma8(sum, w0, x0);
        fma8(sum, w1, x1);
        fma8(sum, w2, x2);
        fma8(sum, w3, x3);
    }
    for (; k < d; ++k) {
        int c = cv[s + k];
        uint4 x = feats16[(size_t)c * 8 + l];
        fma8(sum, invs[c], x);
    }
    float ivr = invs[row];
    uint4 bx = feats16[(size_t)row * 8 + l];
    float base[8] = {bflo(bx.x), bfhi(bx.x), bflo(bx.y), bfhi(bx.y),
                     bflo(bx.z), bfhi(bx.z), bflo(bx.w), bfhi(bx.w)};
    float a[8], fs[8];
    float iv2 = ivr * ivr;
    #pragma unroll
    for (int j = 0; j < 8; ++j) {
        a[j]  = fmaf(ivr, sum[j], base[j]);
        fs[j] = iv2 * sum[j];
    }
    size_t idx = (size_t)row * 8 + l;
    acc16[idx] = pack8(a);
    f1s16[idx] = pack8(fs);
}

// Layer 2: acc16[r] += invs[r] * Σ f1s16[c]
__global__ void layer2_kernel(const int* __restrict__ off,
                              const int* __restrict__ deg,
                              const int* __restrict__ cv,
                              const float* __restrict__ invs,
                              const uint4* __restrict__ f1s16,
                              uint4* __restrict__ acc16) {
    int wave = blockIdx.x * (blockDim.x >> 6) + (threadIdx.x >> 6);
    int sub  = (threadIdx.x >> 3) & 7;
    int l    = threadIdx.x & 7;
    int row  = wave * 8 + sub;
    if (row >= NTOT) return;
    int s = off[row], d = deg[row];
    float sum[8] = {0.f, 0.f, 0.f, 0.f, 0.f, 0.f, 0.f, 0.f};
    int k = 0;
    for (; k + 4 <= d; k += 4) {
        int c0 = cv[s + k + 0];
        int c1 = cv[s + k + 1];
        int c2 = cv[s + k + 2];
        int c3 = cv[s + k + 3];
        uint4 x0 = f1s16[(size_t)c0 * 8 + l];
        uint4 x1 = f1s16[(size_t)c1 * 8 + l];
        uint4 x2 = f1s16[(size_t)c2 * 8 + l];
        uint4 x3 = f1s16[(size_t)c3 * 8 + l];
        fma8(sum, 1.f, x0);
        fma8(sum, 1.f, x1);
        fma8(sum, 1.f, x2);
        fma8(sum, 1.f, x3);
    }
    for (; k < d; ++k) {
        int c = cv[s + k];
        uint4 x = f1s16[(size_t)c * 8 + l];
        fma8(sum, 1.f, x);
    }
    float ivr = invs[row];
    size_t idx = (size_t)row * 8 + l;
    uint4 ax = acc16[idx];
    float a[8] = {bflo(ax.x), bfhi(ax.x), bflo(ax.y), bfhi(ax.y),
                  bflo(ax.z), bfhi(ax.z), bflo(ax.w), bfhi(ax.w)};
    #pragma unroll
    for (int j = 0; j < 8; ++j) a[j] = fmaf(ivr, sum[j], a[j]);
    acc16[idx] = pack8(a);
}

// ---------------------------------------------------------------------------
// Fused bundle-SpMM + BPR loss + finalize. One wave per sample; the sample's
// two bundle reps are computed on the fly from the B-CSR (only ~6.7K of 20K
// bundles are referenced). Last finished block writes out[].
__global__ void score_kernel(const int* __restrict__ offB,
                             const int* __restrict__ degB,
                             const int* __restrict__ cvB,
                             const uint4* __restrict__ acc16,
                             const int* __restrict__ users,
                             const int* __restrict__ bundles,
                             float* __restrict__ loss_sum,
                             int* __restrict__ done,
                             float* __restrict__ out) {
    int tid  = blockIdx.x * blockDim.x + threadIdx.x;
    int smp  = tid >> 6;
    int lane = threadIdx.x & 63;
    int sub  = lane >> 3;     // 8 subgroups of 8 lanes
    int l    = lane & 7;      // dim slice [l*8, l*8+8)

    float pred[2];
    if (smp < BATCH) {
        int u = users[smp];
        uint4 uv = acc16[(size_t)u * 8 + l];
        float uvals[8] = {bflo(uv.x), bfhi(uv.x), bflo(uv.y), bfhi(uv.y),
                          bflo(uv.z), bfhi(uv.z), bflo(uv.w), bfhi(uv.w)};
        #pragma unroll
        for (int j = 0; j < 2; ++j) {
            int bd = bundles[2 * smp + j];
            int s  = offB[bd];
            int d  = degB[bd];
            float part[8] = {0.f, 0.f, 0.f, 0.f, 0.f, 0.f, 0.f, 0.f};
            for (int k = sub; k < d; k += 8) {
                int c = cvB[s + k];
                uint4 x = acc16[(size_t)(NU_ + c) * 8 + l];
                fma8(part, 1.f, x);
            }
            // all-reduce over the 8 subgroups (xor on sub bits 3..5)
            #pragma unroll
            for (int m = 8; m <= 32; m <<= 1) {
                #pragma unroll
                for (int i = 0; i < 8; ++i)
                    part[i] += __shfl_xor(part[i], m, 64);
            }
            // dot with user slice
            float dp = 0.f;
            #pragma unroll
            for (int i = 0; i < 8; ++i) dp = fmaf(part[i], uvals[i], dp);
            // all-reduce over the 8 dim-slices (xor on bits 0..2)
            #pragma unroll
            for (int m = 1; m <= 4; m <<= 1)
                dp += __shfl_xor(dp, m, 64);
            pred[j] = dp * (1.0f / 9.0f) / ((float)d + 1e-8f);
        }
        if (lane == 0) {
            float x = pred[0] - pred[1];
            float lv = fmaxf(-x, 0.0f) + log1pf(expf(-fabsf(x)));
            atomicAdd(loss_sum, lv);
        }
    }
    // last-block finalize
    __syncthreads();
    if (threadIdx.x == 0) {
        __threadfence();
        int old = atomicAdd(done, 1);
        if (old == (int)gridDim.x - 1) {
            float total = atomicAdd(loss_sum, 0.0f);   // coherent read
            out[0] = total * (1.0f / BATCH);
            out[1] = 0.0f;
        }
    }
}

// ---------------------------------------------------------------------------
extern "C" void kernel_launch(void* const* d_in, const int* in_sizes, int n_in,
                              void* d_out, int out_size, void* d_ws, size_t ws_size,
                              hipStream_t stream) {
    const float* uf        = (const float*)d_in[0];
    const float* itf       = (const float*)d_in[1];
    const int*   prop_rows = (const int*)  d_in[4];
    const int*   prop_cols = (const int*)  d_in[5];
    const int*   bi_rows   = (const int*)  d_in[6];
    const int*   bi_cols   = (const int*)  d_in[7];
    const int*   users     = (const int*)  d_in[8];
    const int*   bundles   = (const int*)  d_in[9];
    float* out = (float*)d_out;

    char* ws = (char*)d_ws;
    uint4*        acc16   = (uint4*)       (ws + 0);           // 19.2 MB
    uint4*        f1s16   = (uint4*)       (ws + 19200000);    // 19.2 MB
    uint4*        feats16 = (uint4*)       (ws + 38400000);    // 19.2 MB
    int*          cvP     = (int*)         (ws + 62720000);    // 16 MB
    unsigned int* binnedP = (unsigned int*)(ws + 78720000);    // 16 MB
    int*          cvB     = (int*)         (ws + 94720000);    // 2.4 MB
    unsigned int* binnedB = (unsigned int*)(ws + 97120000);    // 2.4 MB
    int*          degP    = (int*)         (ws + 99520000);
    int*          offP    = (int*)         (ws + 100120000);
    float*        invsP   = (float*)       (ws + 100720000);
    int*          degB    = (int*)         (ws + 101320000);
    int*          offB    = (int*)         (ws + 101400000);
    int*          binoffP = (int*)         (ws + 101480000);
    int*          gcurP   = (int*)         (ws + 101482368);
    int*          binoffB = (int*)         (ws + 101484736);
    int*          gcurB   = (int*)         (ws + 101485056);
    // contiguous zero-init region: bcntP | bcntB | loss | done
    int*          bcntP   = (int*)         (ws + 101485376);   // 2368 B
    int*          bcntB   = (int*)         (ws + 101487744);   // 320 B
    float*        loss    = (float*)       (ws + 101488064);   // 4 B
    int*          done    = (int*)         (ws + 101488068);   // 4 B

    hipMemsetAsync(bcntP, 0, 2696, stream);   // bcntP + bcntB + loss + done

    // 1) cast + histograms (fused)
    prep_kernel<<<CAST_BLOCKS + HISTP_BLOCKS + HISTB_BLOCKS, 256, 0, stream>>>(
        (const float4*)uf, (const float4*)itf, (uint2*)feats16,
        prop_rows, bi_rows, bcntP, bcntB);

    // 2) bin-offset scans (P and B in one launch)
    scan_kernel<<<2, 1024, 0, stream>>>(bcntP, binoffP, gcurP,
                                        bcntB, binoffB, gcurB);

    // 3) staged multisplit (P+B fused, unroll-4)
    multisplit_kernel<<<MSP_BLOCKS + MSB_BLOCKS, 256, 0, stream>>>(
        prop_rows, prop_cols, bi_rows, bi_cols,
        gcurP, binnedP, gcurB, binnedB);

    // 4) per-bin CSR build (P+B fused)
    bin_csr_kernel<<<NBIN_P + NBIN_B, 256, 0, stream>>>(
        binnedP, binoffP, offP, degP, invsP, cvP,
        binnedB, binoffB, offB, degB, cvB);

    // 5-6) propagation
    layer1_kernel<<<(NTOT + 31) / 32, 256, 0, stream>>>(offP, degP, cvP, invsP,
                                                        feats16, f1s16, acc16);
    layer2_kernel<<<(NTOT + 31) / 32, 256, 0, stream>>>(offP, degP, cvP, invsP,
                                                        f1s16, acc16);

    // 7) fused bundle-SpMM + loss + finalize
    score_kernel<<<SCORE_BLOCKS, 256, 0, stream>>>(
        offB, degB, cvB, acc16, users, bundles, loss, done, out);
}

// Round 12
// 462.003 us; speedup vs baseline: 1.1464x; 1.1464x over previous
//
#include <hip/hip_runtime.h>
#include <math.h>

#define NU_    100000
#define NI_    50000
#define NB_    20000
#define DIM    64
#define E_UI_  2000000
#define E_BI_  600000
#define NPROP  (2 * E_UI_)
#define NTOT   (NU_ + NI_)
#define BATCH  4096
#define NBIN_P ((NTOT + 255) / 256)   // 586
#define NBIN_B ((NB_  + 255) / 256)   // 79
// Bin capacity. NOTE: prop rows are NON-uniform — item rows (2M edges over
// 50K rows) give ~10240 expected entries per item bin (user bins ~5120).
// 12288 = 10240 + ~20 sigma. B bins: 7680 expected.
#define CAP    12288

#define MSB_BLOCKS  96
#define MSP_BLOCKS  672
#define MS_TOTAL    (MSB_BLOCKS + MSP_BLOCKS)      // 768 = one full residency wave
#define CAST_BLOCKS ((NTOT * 16) / 256)            // 9375 (exact)
#define SCORE_BLOCKS (BATCH / 4)                   // 1024, one wave per sample

// ---------------------------------------------------------------------------
// bf16 helpers
__device__ __forceinline__ float bflo(unsigned int u) {
    return __uint_as_float(u << 16);
}
__device__ __forceinline__ float bfhi(unsigned int u) {
    return __uint_as_float(u & 0xFFFF0000u);
}
__device__ __forceinline__ unsigned short f2bf(float f) {         // RNE
    unsigned int u = __float_as_uint(f);
    u += 0x7FFFu + ((u >> 16) & 1u);
    return (unsigned short)(u >> 16);
}
__device__ __forceinline__ unsigned int pack2(float a, float b) {
    return (unsigned int)f2bf(a) | ((unsigned int)f2bf(b) << 16);
}

// ---------------------------------------------------------------------------
// Fused multisplit (fixed-capacity bins, no histogram/scan needed) + bf16 cast.
// Block order: [B: 0..96) [P: 96..768) [cast: 768..10143).
// payload = ((row & 255) << 24) | col
__global__ void mscast_kernel(const int* __restrict__ prows,
                              const int* __restrict__ pcols,
                              const int* __restrict__ brows,
                              const int* __restrict__ bcols,
                              int* __restrict__ gcurP,
                              unsigned int* __restrict__ binnedP,
                              int* __restrict__ gcurB,
                              unsigned int* __restrict__ binnedB,
                              const float4* __restrict__ uf4,
                              const float4* __restrict__ itf4,
                              uint2* __restrict__ feats_out) {
    constexpr int BUF = 16;
    __shared__ int cnt[NBIN_P];
    __shared__ int basep[NBIN_P];
    __shared__ unsigned int stage[NBIN_P][BUF];
    int bid = blockIdx.x;
    if (bid >= MS_TOTAL) {
        // ---- cast lane ----
        int i = (bid - MS_TOTAL) * 256 + threadIdx.x;
        const int nuq = NU_ * 16;
        const int totq = NTOT * 16;
        if (i < totq) {
            float4 v = (i < nuq) ? uf4[i] : itf4[i - nuq];
            uint2 o;
            o.x = pack2(v.x, v.y);
            o.y = pack2(v.z, v.w);
            feats_out[i] = o;
        }
        return;
    }
    const int *rows, *cols; int n, nbin, vb, vgrid;
    int* gcur; unsigned int* binned;
    if (bid < MSB_BLOCKS) {
        rows = brows; cols = bcols; n = E_BI_; nbin = NBIN_B;
        vb = bid; vgrid = MSB_BLOCKS; gcur = gcurB; binned = binnedB;
    } else {
        rows = prows; cols = pcols; n = NPROP; nbin = NBIN_P;
        vb = bid - MSB_BLOCKS; vgrid = MSP_BLOCKS; gcur = gcurP; binned = binnedP;
    }
    for (int i = threadIdx.x; i < nbin; i += 256) cnt[i] = 0;
    __syncthreads();
    int stride = vgrid * 256 * 4;
    for (int base = vb * 256 * 4; base < n; base += stride) {
        int bin[4], pos[4];
        unsigned int payload[4];
        #pragma unroll
        for (int j = 0; j < 4; ++j) {
            int i = base + j * 256 + threadIdx.x;   // coalesced per step
            pos[j] = -1;
            if (i < n) {
                int r = rows[i];
                int c = cols[i];
                bin[j] = r >> 8;
                payload[j] = ((unsigned int)(r & 255) << 24) | (unsigned int)c;
                pos[j] = atomicAdd(&cnt[bin[j]], 1);
                if (pos[j] < BUF) stage[bin[j]][pos[j]] = payload[j];
            }
        }
        __syncthreads();
        #pragma unroll
        for (int j = 0; j < 4; ++j)
            if (pos[j] == BUF)                 // unique leader per bin
                basep[bin[j]] = bin[j] * CAP + atomicAdd(&gcur[bin[j]], cnt[bin[j]]);
        __syncthreads();
        #pragma unroll
        for (int j = 0; j < 4; ++j) {
            if (pos[j] >= BUF) {
                binned[basep[bin[j]] + pos[j]] = payload[j];
                if (pos[j] == BUF) {
                    int b0 = basep[bin[j]];
                    #pragma unroll
                    for (int q = 0; q < BUF; ++q) binned[b0 + q] = stage[bin[j]][q];
                    cnt[bin[j]] = 0;
                }
            }
        }
        __syncthreads();
    }
    // per-thread drain: 256 independent atomic+store chains
    for (int b = threadIdx.x; b < nbin; b += 256) {
        int c = cnt[b];
        if (c > 0) {
            int b0 = b * CAP + atomicAdd(&gcur[b], c);
            for (int j = 0; j < c; ++j) binned[b0 + j] = stage[b][j];
        }
    }
}

// ---------------------------------------------------------------------------
// Per-bin CSR build (P: blocks [0,586), B: [586,665)). The whole bin is staged
// through LDS, so cv may ALIAS binned (in-place rewrite): all global reads of
// the bin complete before any cv write.
__global__ void bin_csr_kernel(unsigned int* __restrict__ binnedP,
                               const int* __restrict__ gcurP,
                               int* __restrict__ offP, int* __restrict__ degP,
                               float* __restrict__ invsP,
                               unsigned int* __restrict__ binnedB,
                               const int* __restrict__ gcurB,
                               int* __restrict__ offB, int* __restrict__ degB) {
    __shared__ unsigned int ebuf[CAP];        // 48 KB
    __shared__ int cnt[256];
    __shared__ int cur[256];
    __shared__ int scanbuf[256];
    unsigned int* binned; const int* gcur;
    int* off; int* deg; float* invs;
    int b, nrows;
    if (blockIdx.x < NBIN_P) {
        b = blockIdx.x; binned = binnedP; gcur = gcurP; nrows = NTOT;
        off = offP; deg = degP; invs = invsP;
    } else {
        b = blockIdx.x - NBIN_P; binned = binnedB; gcur = gcurB; nrows = NB_;
        off = offB; deg = degB; invs = (float*)0;
    }
    int t = threadIdx.x;
    int rowbase = b << 8;
    int s = b * CAP;
    int m = gcur[b];
    if (m > CAP) m = CAP;                     // defensive clamp
    // stage bin into LDS (coalesced)
    for (int i = t; i < m; i += 256) ebuf[i] = binned[s + i];
    cnt[t] = 0;
    __syncthreads();
    for (int i = t; i < m; i += 256)
        atomicAdd(&cnt[ebuf[i] >> 24], 1);
    __syncthreads();
    int x = cnt[t];
    scanbuf[t] = x;
    __syncthreads();
    for (int o = 1; o < 256; o <<= 1) {
        int y = (t >= o) ? scanbuf[t - o] : 0;
        __syncthreads();
        scanbuf[t] += y;
        __syncthreads();
    }
    int base = s + scanbuf[t] - x;            // bin-local exclusive scan
    cur[t] = base;
    if (rowbase + t < nrows) {
        off[rowbase + t] = base;
        deg[rowbase + t] = x;
        if (invs) invs[rowbase + t] = 1.0f / (sqrtf((float)x) + 1e-8f);
    }
    __syncthreads();
    // in-place cv fill from LDS copy
    for (int i = t; i < m; i += 256) {
        unsigned int p = ebuf[i];
        int slot = atomicAdd(&cur[p >> 24], 1);
        binned[slot] = p & 0xFFFFFFu;
    }
}

// ---------------------------------------------------------------------------
// 8 lanes/row, uint4 = 8 bf16 per lane. 8 rows/wave, 32 rows per 256-block.
__device__ __forceinline__ void fma8(float* s, float v, uint4 x) {
    s[0] = fmaf(v, bflo(x.x), s[0]);
    s[1] = fmaf(v, bfhi(x.x), s[1]);
    s[2] = fmaf(v, bflo(x.y), s[2]);
    s[3] = fmaf(v, bfhi(x.y), s[3]);
    s[4] = fmaf(v, bflo(x.z), s[4]);
    s[5] = fmaf(v, bfhi(x.z), s[5]);
    s[6] = fmaf(v, bflo(x.w), s[6]);
    s[7] = fmaf(v, bfhi(x.w), s[7]);
}
__device__ __forceinline__ uint4 pack8(const float* s) {
    uint4 o;
    o.x = pack2(s[0], s[1]);
    o.y = pack2(s[2], s[3]);
    o.z = pack2(s[4], s[5]);
    o.w = pack2(s[6], s[7]);
    return o;
}

// Layer 1: sum = Σ invs[c]·feats[c]; acc16[r] = feats[r] + invs[r]·sum;
//          f1s16[r] = invs[r]²·sum
__global__ void layer1_kernel(const int* __restrict__ off,
                              const int* __restrict__ deg,
                              const unsigned int* __restrict__ cv,
                              const float* __restrict__ invs,
                              const uint4* __restrict__ feats16,
                              uint4* __restrict__ f1s16,
                              uint4* __restrict__ acc16) {
    int wave = blockIdx.x * (blockDim.x >> 6) + (threadIdx.x >> 6);
    int sub  = (threadIdx.x >> 3) & 7;
    int l    = threadIdx.x & 7;
    int row  = wave * 8 + sub;
    if (row >= NTOT) return;
    int s = off[row], d = deg[row];
    float sum[8] = {0.f, 0.f, 0.f, 0.f, 0.f, 0.f, 0.f, 0.f};
    int k = 0;
    for (; k + 4 <= d; k += 4) {
        int c0 = (int)cv[s + k + 0];
        int c1 = (int)cv[s + k + 1];
        int c2 = (int)cv[s + k + 2];
        int c3 = (int)cv[s + k + 3];
        float w0 = invs[c0], w1 = invs[c1], w2 = invs[c2], w3 = invs[c3];
        uint4 x0 = feats16[(size_t)c0 * 8 + l];
        uint4 x1 = feats16[(size_t)c1 * 8 + l];
        uint4 x2 = feats16[(size_t)c2 * 8 + l];
        uint4 x3 = feats16[(size_t)c3 * 8 + l];
        fma8(sum, w0, x0);
        fma8(sum, w1, x1);
        fma8(sum, w2, x2);
        fma8(sum, w3, x3);
    }
    for (; k < d; ++k) {
        int c = (int)cv[s + k];
        uint4 x = feats16[(size_t)c * 8 + l];
        fma8(sum, invs[c], x);
    }
    float ivr = invs[row];
    uint4 bx = feats16[(size_t)row * 8 + l];
    float base[8] = {bflo(bx.x), bfhi(bx.x), bflo(bx.y), bfhi(bx.y),
                     bflo(bx.z), bfhi(bx.z), bflo(bx.w), bfhi(bx.w)};
    float a[8], fs[8];
    float iv2 = ivr * ivr;
    #pragma unroll
    for (int j = 0; j < 8; ++j) {
        a[j]  = fmaf(ivr, sum[j], base[j]);
        fs[j] = iv2 * sum[j];
    }
    size_t idx = (size_t)row * 8 + l;
    acc16[idx] = pack8(a);
    f1s16[idx] = pack8(fs);
}

// Layer 2: acc16[r] += invs[r] * Σ f1s16[c]
__global__ void layer2_kernel(const int* __restrict__ off,
                              const int* __restrict__ deg,
                              const unsigned int* __restrict__ cv,
                              const float* __restrict__ invs,
                              const uint4* __restrict__ f1s16,
                              uint4* __restrict__ acc16) {
    int wave = blockIdx.x * (blockDim.x >> 6) + (threadIdx.x >> 6);
    int sub  = (threadIdx.x >> 3) & 7;
    int l    = threadIdx.x & 7;
    int row  = wave * 8 + sub;
    if (row >= NTOT) return;
    int s = off[row], d = deg[row];
    float sum[8] = {0.f, 0.f, 0.f, 0.f, 0.f, 0.f, 0.f, 0.f};
    int k = 0;
    for (; k + 4 <= d; k += 4) {
        int c0 = (int)cv[s + k + 0];
        int c1 = (int)cv[s + k + 1];
        int c2 = (int)cv[s + k + 2];
        int c3 = (int)cv[s + k + 3];
        uint4 x0 = f1s16[(size_t)c0 * 8 + l];
        uint4 x1 = f1s16[(size_t)c1 * 8 + l];
        uint4 x2 = f1s16[(size_t)c2 * 8 + l];
        uint4 x3 = f1s16[(size_t)c3 * 8 + l];
        fma8(sum, 1.f, x0);
        fma8(sum, 1.f, x1);
        fma8(sum, 1.f, x2);
        fma8(sum, 1.f, x3);
    }
    for (; k < d; ++k) {
        int c = (int)cv[s + k];
        uint4 x = f1s16[(size_t)c * 8 + l];
        fma8(sum, 1.f, x);
    }
    float ivr = invs[row];
    size_t idx = (size_t)row * 8 + l;
    uint4 ax = acc16[idx];
    float a[8] = {bflo(ax.x), bfhi(ax.x), bflo(ax.y), bfhi(ax.y),
                  bflo(ax.z), bfhi(ax.z), bflo(ax.w), bfhi(ax.w)};
    #pragma unroll
    for (int j = 0; j < 8; ++j) a[j] = fmaf(ivr, sum[j], a[j]);
    acc16[idx] = pack8(a);
}

// ---------------------------------------------------------------------------
// Fused bundle-SpMM + BPR loss + finalize. One wave per sample.
__global__ void score_kernel(const int* __restrict__ offB,
                             const int* __restrict__ degB,
                             const unsigned int* __restrict__ cvB,
                             const uint4* __restrict__ acc16,
                             const int* __restrict__ users,
                             const int* __restrict__ bundles,
                             float* __restrict__ loss_sum,
                             int* __restrict__ done,
                             float* __restrict__ out) {
    int tid  = blockIdx.x * blockDim.x + threadIdx.x;
    int smp  = tid >> 6;
    int lane = threadIdx.x & 63;
    int sub  = lane >> 3;     // 8 subgroups of 8 lanes
    int l    = lane & 7;      // dim slice [l*8, l*8+8)

    float pred[2];
    if (smp < BATCH) {
        int u = users[smp];
        uint4 uv = acc16[(size_t)u * 8 + l];
        float uvals[8] = {bflo(uv.x), bfhi(uv.x), bflo(uv.y), bfhi(uv.y),
                          bflo(uv.z), bfhi(uv.z), bflo(uv.w), bfhi(uv.w)};
        #pragma unroll
        for (int j = 0; j < 2; ++j) {
            int bd = bundles[2 * smp + j];
            int s  = offB[bd];
            int d  = degB[bd];
            float part[8] = {0.f, 0.f, 0.f, 0.f, 0.f, 0.f, 0.f, 0.f};
            for (int k = sub; k < d; k += 8) {
                int c = (int)cvB[s + k];
                uint4 x = acc16[(size_t)(NU_ + c) * 8 + l];
                fma8(part, 1.f, x);
            }
            #pragma unroll
            for (int m = 8; m <= 32; m <<= 1) {
                #pragma unroll
                for (int i = 0; i < 8; ++i)
                    part[i] += __shfl_xor(part[i], m, 64);
            }
            float dp = 0.f;
            #pragma unroll
            for (int i = 0; i < 8; ++i) dp = fmaf(part[i], uvals[i], dp);
            #pragma unroll
            for (int m = 1; m <= 4; m <<= 1)
                dp += __shfl_xor(dp, m, 64);
            pred[j] = dp * (1.0f / 9.0f) / ((float)d + 1e-8f);
        }
        if (lane == 0) {
            float x = pred[0] - pred[1];
            float lv = fmaxf(-x, 0.0f) + log1pf(expf(-fabsf(x)));
            atomicAdd(loss_sum, lv);
        }
    }
    __syncthreads();
    if (threadIdx.x == 0) {
        __threadfence();
        int old = atomicAdd(done, 1);
        if (old == (int)gridDim.x - 1) {
            float total = atomicAdd(loss_sum, 0.0f);   // coherent read
            out[0] = total * (1.0f / BATCH);
            out[1] = 0.0f;
        }
    }
}

// ---------------------------------------------------------------------------
extern "C" void kernel_launch(void* const* d_in, const int* in_sizes, int n_in,
                              void* d_out, int out_size, void* d_ws, size_t ws_size,
                              hipStream_t stream) {
    const float* uf        = (const float*)d_in[0];
    const float* itf       = (const float*)d_in[1];
    const int*   prop_rows = (const int*)  d_in[4];
    const int*   prop_cols = (const int*)  d_in[5];
    const int*   bi_rows   = (const int*)  d_in[6];
    const int*   bi_cols   = (const int*)  d_in[7];
    const int*   users     = (const int*)  d_in[8];
    const int*   bundles   = (const int*)  d_in[9];
    float* out = (float*)d_out;

    char* ws = (char*)d_ws;
    uint4*        acc16   = (uint4*)       (ws + 0);            // 19.2 MB
    uint4*        f1s16   = (uint4*)       (ws + 19200000);     // 19.2 MB
    uint4*        feats16 = (uint4*)       (ws + 38400000);     // 19.2 MB
    unsigned int* binnedP = (unsigned int*)(ws + 57600000);     // 586*12288*4 = 28.8 MB (cv in-place)
    unsigned int* binnedB = (unsigned int*)(ws + 86403072);     // 79*12288*4 = 3.88 MB
    int*          degP    = (int*)         (ws + 90286080);
    int*          offP    = (int*)         (ws + 90886080);
    float*        invsP   = (float*)       (ws + 91486080);
    int*          degB    = (int*)         (ws + 92086080);
    int*          offB    = (int*)         (ws + 92166080);
    // contiguous zero-init region: gcurP | gcurB | loss | done
    int*          gcurP   = (int*)         (ws + 92246080);     // 2344 B
    int*          gcurB   = (int*)         (ws + 92248424);     // 316 B
    float*        loss    = (float*)       (ws + 92248740);     // 4 B
    int*          done    = (int*)         (ws + 92248744);     // 4 B

    hipMemsetAsync(gcurP, 0, 2668, stream);   // gcurP + gcurB + loss + done

    // 1) fused multisplit (fixed-cap bins) + bf16 cast
    mscast_kernel<<<MS_TOTAL + CAST_BLOCKS, 256, 0, stream>>>(
        prop_rows, prop_cols, bi_rows, bi_cols,
        gcurP, binnedP, gcurB, binnedB,
        (const float4*)uf, (const float4*)itf, (uint2*)feats16);

    // 2) per-bin CSR build, in-place via LDS staging (P+B fused)
    bin_csr_kernel<<<NBIN_P + NBIN_B, 256, 0, stream>>>(
        binnedP, gcurP, offP, degP, invsP,
        binnedB, gcurB, offB, degB);

    // 3-4) propagation
    layer1_kernel<<<(NTOT + 31) / 32, 256, 0, stream>>>(offP, degP, binnedP, invsP,
                                                        feats16, f1s16, acc16);
    layer2_kernel<<<(NTOT + 31) / 32, 256, 0, stream>>>(offP, degP, binnedP, invsP,
                                                        f1s16, acc16);

    // 5) fused bundle-SpMM + loss + finalize
    score_kernel<<<SCORE_BLOCKS, 256, 0, stream>>>(
        offB, degB, binnedB, acc16, users, bundles, loss, done, out);
}